// Round 9
// baseline (948.838 us; speedup 1.0000x reference)
//
#include <hip/hip_runtime.h>

#define HIDDEN 1024
#define NTOK (8 * 2048)   // B*S = 16384 tokens
#define BM 256
#define BN 128
#define BK 32
#define NT (HIDDEN / BK)  // 32 K-tiles

typedef __attribute__((ext_vector_type(4))) float f32x4;
typedef __attribute__((ext_vector_type(8))) short bf16x8;
typedef __attribute__((ext_vector_type(4))) unsigned short u16x4;
typedef __attribute__((ext_vector_type(8))) unsigned short u16x8;

typedef __attribute__((address_space(3))) unsigned int lds_u32;
typedef __attribute__((address_space(1))) unsigned int glb_u32;

__device__ inline unsigned short f2b(float f) {
    unsigned int u = __float_as_uint(f);
    u += 0x7fffu + ((u >> 16) & 1u);   // round-to-nearest-even
    return (unsigned short)(u >> 16);
}
__device__ inline float b2f(unsigned short u) {
    return __uint_as_float(((unsigned int)u) << 16);
}

// ---------------- fp32 -> bf16 convert, all 4 arrays in one launch ----------
__global__ __launch_bounds__(256) void cvt_all(
    const float4* __restrict__ x1, const float4* __restrict__ wq,
    const float4* __restrict__ wk, const float4* __restrict__ wv,
    u16x4* __restrict__ dst) {
    const int NX = NTOK * HIDDEN / 4;
    const int NW = HIDDEN * HIDDEN / 4;
    const int total = NX + 3 * NW;
    const int stride = gridDim.x * blockDim.x;
    for (int i = blockIdx.x * blockDim.x + threadIdx.x; i < total; i += stride) {
        const float4* s; int o;
        if (i < NX)               { s = x1; o = i; }
        else if (i < NX + NW)     { s = wq; o = i - NX; }
        else if (i < NX + 2 * NW) { s = wk; o = i - NX - NW; }
        else                      { s = wv; o = i - NX - 2 * NW; }
        float4 x = s[o];
        u16x4 r;
        r[0] = f2b(x.x); r[1] = f2b(x.y); r[2] = f2b(x.z); r[3] = f2b(x.w);
        dst[i] = r;
    }
}

// per-wave attention for tokens [tok0 + wave*16, +16). LDS carved from sb.
// K_lds-style XOR swizzle: global 8-elem slot s of row r stored at slot s^r
// -> reads at fixed s hit 8 distinct bank groups across rows (conflict-free).
__device__ inline void run_attn_group(const unsigned short* __restrict__ QKV,
                                      float* __restrict__ out,
                                      unsigned short* lds, int lane, int wave,
                                      int tok0) {
    unsigned short* aQ = lds + wave * 3328;
    unsigned short* aK = aQ + 1024;
    unsigned short* aV = aK + 1024;
    float* aA = (float*)(aV + 1024);            // 64 floats
    const size_t NH = (size_t)NTOK * HIDDEN;
    const int h = lane >> 3, gsl = lane & 7;
    const int rw = lane >> 3, s0 = (lane & 7) * 2;   // staging coords
    const int wo0 = rw * 128 + ((s0 ^ rw) * 8);
    const int wo1 = rw * 128 + (((s0 + 1) ^ rw) * 8);

    for (int it = 0; it < 16; ++it) {
        const int token = tok0 + wave * 16 + it;
        const size_t tb = (size_t)token * HIDDEN + lane * 16;
        u16x8 rq0 = *(const u16x8*)(QKV + tb);
        u16x8 rq1 = *(const u16x8*)(QKV + tb + 8);
        u16x8 rk0 = *(const u16x8*)(QKV + NH + tb);
        u16x8 rk1 = *(const u16x8*)(QKV + NH + tb + 8);
        u16x8 rv0 = *(const u16x8*)(QKV + 2 * NH + tb);
        u16x8 rv1 = *(const u16x8*)(QKV + 2 * NH + tb + 8);
        *(u16x8*)(aQ + wo0) = rq0;  *(u16x8*)(aQ + wo1) = rq1;
        *(u16x8*)(aK + wo0) = rk0;  *(u16x8*)(aK + wo1) = rk1;
        *(u16x8*)(aV + wo0) = rv0;  *(u16x8*)(aV + wo1) = rv1;
        asm volatile("s_waitcnt lgkmcnt(0)" ::: "memory");
        __builtin_amdgcn_sched_barrier(0);

        float sc = 0.f;
#pragma unroll
        for (int s = 0; s < 16; ++s) {           // s = global 8-elem d-slot
            u16x8 qv = *(const u16x8*)(aQ + h * 128 + ((s ^ h) * 8));
            u16x8 kv = *(const u16x8*)(aK + gsl * 128 + ((s ^ gsl) * 8));
#pragma unroll
            for (int j = 0; j < 8; ++j) sc += b2f(qv[j]) * b2f(kv[j]);
        }
        sc *= -0.08838834764831845f;   // NEGATED scale, faithful to source quirk

        float mx = sc;
#pragma unroll
        for (int o = 1; o < 8; o <<= 1) mx = fmaxf(mx, __shfl_xor(mx, o, 64));
        const float e = __expf(sc - mx);
        float sm = e;
#pragma unroll
        for (int o = 1; o < 8; o <<= 1) sm += __shfl_xor(sm, o, 64);
        aA[lane] = e / sm;
        asm volatile("s_waitcnt lgkmcnt(0)" ::: "memory");
        __builtin_amdgcn_sched_barrier(0);

        float ov[16];
#pragma unroll
        for (int j = 0; j < 16; ++j) ov[j] = 0.f;
        const int c2 = (lane & 7) * 2;
#pragma unroll
        for (int gg = 0; gg < 8; ++gg) {
            const float a = aA[h * 8 + gg];
            u16x8 v0 = *(const u16x8*)(aV + gg * 128 + ((c2 ^ gg) * 8));
            u16x8 v1 = *(const u16x8*)(aV + gg * 128 + (((c2 + 1) ^ gg) * 8));
#pragma unroll
            for (int j = 0; j < 8; ++j) {
                ov[j]     += a * b2f(v0[j]);
                ov[8 + j] += a * b2f(v1[j]);
            }
        }
        float* op = out + (size_t)token * HIDDEN + lane * 16;
#pragma unroll
        for (int j = 0; j < 16; j += 4)
            *(float4*)&op[j] = make_float4(ov[j], ov[j+1], ov[j+2], ov[j+3]);
    }
}

// ---------------- fused QKV GEMM + finisher attention -----------------------
// GEMM core = R5's verified 256x128 / 4-wave / dbuf-48KB structure (906 TF).
// Map is mt-major: bids [mt*24, mt*24+24) are the 24 writers of m-tile mt
// (3 mats x 8 col-blocks). After the epilogue each block release-fences and
// atomicAdds the mt's 4 sub-counters; the 24th arriver on counter q runs
// attention for tokens [mt*256+q*64, +64) (data is L2/L3-hot). Finisher work
// rides in the GEMM's idle issue slots (MfmaUtil 40 + VALUBusy 22 measured).
__global__ __launch_bounds__(256, 2) void qkv_gemm(
    const unsigned short* __restrict__ Xb,
    const unsigned short* __restrict__ Wb,
    const float* __restrict__ bqp, const float* __restrict__ bkp,
    const float* __restrict__ bvp,
    unsigned short* __restrict__ QKV,
    float* __restrict__ out, int* __restrict__ cnt) {
    // per buffer: A 256x32 (16 KB) @ [0..8191], B 128x32 (8 KB) @ [8192..12287]
    __shared__ __align__(16) unsigned short sb[2][12288];
    __shared__ int sflag[4];

    const int tid = threadIdx.x;
    const int lane = tid & 63, wave = tid >> 6;
    const int wm = wave >> 1, wn = wave & 1;      // 2x2 wave grid, 128x64 each

    // mt-major map: 24 consecutive blocks share one m-tile.
    const int bid = blockIdx.x;
    const int mt = bid / 24;                 // 0..63
    const int nt = bid % 24;                 // 0..23
    const int mat = nt >> 3;                 // 0=q 1=k 2=v
    const int col0 = (nt & 7) * BN;
    const int row0 = mt * BM;

    const unsigned short* Ag = Xb + (size_t)row0 * HIDDEN;
    const unsigned short* Bg = Wb + (size_t)mat * (HIDDEN * HIDDEN)
                                  + (size_t)col0 * HIDDEN;
    const float* bias = (mat == 0) ? bqp : ((mat == 1) ? bkp : bvp);
    unsigned short* Out = QKV + (size_t)mat * ((size_t)NTOK * HIDDEN);

    // staging: 1536 16B-chunks (A:1024, B:512), 6 per thread (256 thr).
    // source col pre-swizzled: slot ^ ((row>>1)&3); LDS dest linear.
    const unsigned short* srcb[6];
    int dstoff[6];
#pragma unroll
    for (int c = 0; c < 6; ++c) {
        const int gidx = c * 256 + tid;
        const int slot = gidx & 3;
        if (gidx < 1024) {
            const int r = gidx >> 2;
            srcb[c] = Ag + (size_t)r * HIDDEN + (slot ^ ((r >> 1) & 3)) * 8;
        } else {
            const int r = (gidx - 1024) >> 2;
            srcb[c] = Bg + (size_t)r * HIDDEN + (slot ^ ((r >> 1) & 3)) * 8;
        }
        dstoff[c] = gidx * 8;
    }

    // frag read bases (halfword offsets), swizzled k-slot
    const int fr = lane & 15;
    const int kq = lane >> 4;            // 16B slot within 32-elem row
    const int sx = (fr >> 1) & 3;
    const int aoff = (wm * 128 + fr) * BK + ((kq ^ sx) * 8);
    const int boff = 8192 + (wn * 64 + fr) * BK + ((kq ^ sx) * 8);

    // prologue: stage tile 0
#pragma unroll
    for (int c = 0; c < 6; ++c)
        __builtin_amdgcn_global_load_lds((const glb_u32*)(srcb[c]),
                                         (lds_u32*)(&sb[0][0] + dstoff[c]), 16, 0, 0);
    __syncthreads();

    f32x4 acc[8][4] = {};

#pragma unroll 2
    for (int j = 0; j < NT; ++j) {
        if (j + 1 < NT) {
            unsigned short* dbuf = &sb[(j + 1) & 1][0];
#pragma unroll
            for (int c = 0; c < 6; ++c)
                __builtin_amdgcn_global_load_lds(
                    (const glb_u32*)(srcb[c] + (j + 1) * BK),
                    (lds_u32*)(dbuf + dstoff[c]), 16, 0, 0);
        }
        const unsigned short* buf = &sb[j & 1][0];
        bf16x8 bfr[4];
#pragma unroll
        for (int n = 0; n < 4; ++n)
            bfr[n] = *(const bf16x8*)(buf + boff + n * (16 * BK));
#pragma unroll
        for (int m = 0; m < 8; ++m) {
            const bf16x8 afr = *(const bf16x8*)(buf + aoff + m * (16 * BK));
#pragma unroll
            for (int n = 0; n < 4; ++n)
                acc[m][n] = __builtin_amdgcn_mfma_f32_16x16x32_bf16(
                    afr, bfr[n], acc[m][n], 0, 0, 0);
        }
        __syncthreads();
    }

    // epilogue: bias add, bf16 store. C/D map: col=lane&15, row=(lane>>4)*4+jj
    const int fq = lane >> 4;
    float bvv[4];
#pragma unroll
    for (int n = 0; n < 4; ++n) bvv[n] = bias[col0 + wn * 64 + n * 16 + fr];
#pragma unroll
    for (int m = 0; m < 8; ++m) {
#pragma unroll
        for (int n = 0; n < 4; ++n) {
            const int colg = col0 + wn * 64 + n * 16 + fr;
#pragma unroll
            for (int jj = 0; jj < 4; ++jj) {
                const int rowg = row0 + wm * 128 + m * 16 + fq * 4 + jj;
                Out[(size_t)rowg * HIDDEN + colg] = f2b(acc[m][n][jj] + bvv[n]);
            }
        }
    }

    // ---- finisher: count writers of this m-tile; 24th arriver runs attention
    __syncthreads();                   // drains vmcnt(0): all stores in L2 path
    if (tid < 4) {
        __threadfence();               // release: write-back before counting
        const int old = atomicAdd(&cnt[mt * 4 + tid], 1);
        sflag[tid] = (old == 23) ? 1 : 0;
    }
    __syncthreads();
#pragma unroll
    for (int q = 0; q < 4; ++q) {
        if (sflag[q]) {
            __threadfence();           // acquire: invalidate stale cache lines
            run_attn_group(QKV, out, &sb[0][0], lane, wave, row0 + q * 64);
        }
    }
}

extern "C" void kernel_launch(void* const* d_in, const int* in_sizes, int n_in,
                              void* d_out, int out_size, void* d_ws, size_t ws_size,
                              hipStream_t stream) {
    const float* x1 = (const float*)d_in[0];
    const float* Wq = (const float*)d_in[1];
    const float* bq = (const float*)d_in[2];
    const float* Wk = (const float*)d_in[3];
    const float* bk = (const float*)d_in[4];
    const float* Wv = (const float*)d_in[5];
    const float* bv = (const float*)d_in[6];
    float* out = (float*)d_out;

    // workspace: Xb | Wb(q,k,v) | QKV | cnt[256]  -> 140.5 MB + 1 KB
    unsigned short* Xb  = (unsigned short*)d_ws;
    unsigned short* Wb  = Xb + (size_t)NTOK * HIDDEN;
    unsigned short* QKV = Wb + 3 * (size_t)HIDDEN * HIDDEN;
    int* cnt = (int*)(QKV + 3 * (size_t)NTOK * HIDDEN);

    hipMemsetAsync(cnt, 0, 256 * sizeof(int), stream);

    cvt_all<<<2048, 256, 0, stream>>>((const float4*)x1, (const float4*)Wq,
                                      (const float4*)Wk, (const float4*)Wv,
                                      (u16x4*)Xb);

    qkv_gemm<<<dim3(1536), 256, 0, stream>>>(Xb, Wb, bq, bk, bv, QKV, out, cnt);
}

// Round 10
// 162.218 us; speedup vs baseline: 5.8492x; 5.8492x over previous
//
#include <hip/hip_runtime.h>

#define HIDDEN 1024
#define NTOK (8 * 2048)   // B*S = 16384 tokens
#define BM 256
#define BN 128
#define BK 32
#define NT (HIDDEN / BK)  // 32 K-tiles

typedef __attribute__((ext_vector_type(4))) float f32x4;
typedef __attribute__((ext_vector_type(8))) short bf16x8;
typedef __attribute__((ext_vector_type(4))) unsigned short u16x4;
typedef __attribute__((ext_vector_type(8))) unsigned short u16x8;

typedef __attribute__((address_space(3))) unsigned int lds_u32;
typedef __attribute__((address_space(1))) unsigned int glb_u32;

__device__ inline unsigned short f2b(float f) {
    unsigned int u = __float_as_uint(f);
    u += 0x7fffu + ((u >> 16) & 1u);   // round-to-nearest-even
    return (unsigned short)(u >> 16);
}
__device__ inline float b2f(unsigned short u) {
    return __uint_as_float(((unsigned int)u) << 16);
}

// ---------------- fp32 -> bf16 convert, all 4 arrays in one launch ----------
// At the HBM roofline: 76 MB fp32 read + 38 MB bf16 write ~ 18 us ideal.
__global__ __launch_bounds__(256) void cvt_all(
    const float4* __restrict__ x1, const float4* __restrict__ wq,
    const float4* __restrict__ wk, const float4* __restrict__ wv,
    u16x4* __restrict__ dst) {
    const int NX = NTOK * HIDDEN / 4;
    const int NW = HIDDEN * HIDDEN / 4;
    const int total = NX + 3 * NW;
    const int stride = gridDim.x * blockDim.x;
    for (int i = blockIdx.x * blockDim.x + threadIdx.x; i < total; i += stride) {
        const float4* s; int o;
        if (i < NX)               { s = x1; o = i; }
        else if (i < NX + NW)     { s = wq; o = i - NX; }
        else if (i < NX + 2 * NW) { s = wk; o = i - NX - NW; }
        else                      { s = wv; o = i - NX - 2 * NW; }
        float4 x = s[o];
        u16x4 r;
        r[0] = f2b(x.x); r[1] = f2b(x.y); r[2] = f2b(x.z); r[3] = f2b(x.w);
        dst[i] = r;
    }
}

// ---------------- fused QKV GEMM: 256x128 tile, 4 waves of 128x64 -----------
// C = X (16384x1024) * W^T + bias ; 64 m-tiles x 24 n-tiles = 1536 blocks.
// Structural ceiling note (R1-R9): at K=1024 (16 K-tile pipeline) this
// structure measures 906 TF with DS-pipe (~1536 cyc/pair) + MFMA (~1242)
// sum-packed at 98% of the 2830-cyc period. Five schedule variants
// (8-wave, counted-vmcnt prefetch-2/3, register frag-pipelining, two
// 8-phase ports) landed 112-141 us; zero-LDS and fused-finisher regressed
// 2.5-8x. Documented plain-HIP K=1024 best (m248 full stack: 848 TF) is
// BELOW this kernel. Do not re-attack the schedule without new evidence.
// Swizzle: 16B slot ^= (row>>1)&3 -> frag reads conflict-free (PMC = 0).
__global__ __launch_bounds__(256, 2) void qkv_gemm(
    const unsigned short* __restrict__ Xb,
    const unsigned short* __restrict__ Wb,
    const float* __restrict__ bqp, const float* __restrict__ bkp,
    const float* __restrict__ bvp,
    unsigned short* __restrict__ QKV) {
    // per buffer: A 256x32 (16 KB) @ [0..8191], B 128x32 (8 KB) @ [8192..12287]
    __shared__ __align__(16) unsigned short sb[2][12288];

    const int tid = threadIdx.x;
    const int lane = tid & 63, wave = tid >> 6;
    const int wm = wave >> 1, wn = wave & 1;      // 2x2 wave grid, 128x64 each

    // 2D super-tile XCD map: 64 super-tiles of (4 mt x 6 nt) = 24 blocks.
    const int bid = blockIdx.x;
    const int xcd = bid & 7;
    const int i6 = bid >> 3;            // 0..191
    const int st = i6 / 24;             // 0..7
    const int w = i6 % 24;              // 0..23
    const int g = xcd * 8 + st;         // global super-tile 0..63
    const int mt = (g >> 2) * 4 + w / 6;    // 0..63
    const int nt = (g & 3) * 6 + w % 6;     // 0..23
    const int mat = nt >> 3;                // 0=q 1=k 2=v
    const int col0 = (nt & 7) * BN;
    const int row0 = mt * BM;

    const unsigned short* Ag = Xb + (size_t)row0 * HIDDEN;
    const unsigned short* Bg = Wb + (size_t)mat * (HIDDEN * HIDDEN)
                                  + (size_t)col0 * HIDDEN;
    const float* bias = (mat == 0) ? bqp : ((mat == 1) ? bkp : bvp);
    unsigned short* Out = QKV + (size_t)mat * ((size_t)NTOK * HIDDEN);

    // staging: 1536 16B-chunks (A:1024, B:512), 6 per thread (256 thr).
    // source col pre-swizzled: slot ^ ((row>>1)&3); LDS dest linear.
    const unsigned short* srcb[6];
    int dstoff[6];
#pragma unroll
    for (int c = 0; c < 6; ++c) {
        const int gidx = c * 256 + tid;
        const int slot = gidx & 3;
        if (gidx < 1024) {
            const int r = gidx >> 2;
            srcb[c] = Ag + (size_t)r * HIDDEN + (slot ^ ((r >> 1) & 3)) * 8;
        } else {
            const int r = (gidx - 1024) >> 2;
            srcb[c] = Bg + (size_t)r * HIDDEN + (slot ^ ((r >> 1) & 3)) * 8;
        }
        dstoff[c] = gidx * 8;
    }

    // frag read bases (halfword offsets), swizzled k-slot
    const int fr = lane & 15;
    const int kq = lane >> 4;            // 16B slot within 32-elem row
    const int sx = (fr >> 1) & 3;
    const int aoff = (wm * 128 + fr) * BK + ((kq ^ sx) * 8);
    const int boff = 8192 + (wn * 64 + fr) * BK + ((kq ^ sx) * 8);

    // prologue: stage tile 0
#pragma unroll
    for (int c = 0; c < 6; ++c)
        __builtin_amdgcn_global_load_lds((const glb_u32*)(srcb[c]),
                                         (lds_u32*)(&sb[0][0] + dstoff[c]), 16, 0, 0);
    __syncthreads();

    f32x4 acc[8][4] = {};

#pragma unroll 2
    for (int j = 0; j < NT; ++j) {
        // stage next tile into the other buffer
        if (j + 1 < NT) {
            unsigned short* dbuf = &sb[(j + 1) & 1][0];
#pragma unroll
            for (int c = 0; c < 6; ++c)
                __builtin_amdgcn_global_load_lds(
                    (const glb_u32*)(srcb[c] + (j + 1) * BK),
                    (lds_u32*)(dbuf + dstoff[c]), 16, 0, 0);
        }
        // compute current tile: 4 B-frags held, 8 A-frags streamed
        const unsigned short* buf = &sb[j & 1][0];
        bf16x8 bfr[4];
#pragma unroll
        for (int n = 0; n < 4; ++n)
            bfr[n] = *(const bf16x8*)(buf + boff + n * (16 * BK));
#pragma unroll
        for (int m = 0; m < 8; ++m) {
            const bf16x8 afr = *(const bf16x8*)(buf + aoff + m * (16 * BK));
#pragma unroll
            for (int n = 0; n < 4; ++n)
                acc[m][n] = __builtin_amdgcn_mfma_f32_16x16x32_bf16(
                    afr, bfr[n], acc[m][n], 0, 0, 0);
        }
        __syncthreads();   // drains vmcnt (stage j+1); other block covers
    }

    // epilogue: bias add, bf16 store. C/D map: col=lane&15, row=(lane>>4)*4+jj
    const int fq = lane >> 4;
    float bvv[4];
#pragma unroll
    for (int n = 0; n < 4; ++n) bvv[n] = bias[col0 + wn * 64 + n * 16 + fr];
#pragma unroll
    for (int m = 0; m < 8; ++m) {
#pragma unroll
        for (int n = 0; n < 4; ++n) {
            const int colg = col0 + wn * 64 + n * 16 + fr;
#pragma unroll
            for (int jj = 0; jj < 4; ++jj) {
                const int rowg = row0 + wm * 128 + m * 16 + fq * 4 + jj;
                Out[(size_t)rowg * HIDDEN + colg] = f2b(acc[m][n][jj] + bvv[n]);
            }
        }
    }
}

// ---------------- per-token attention over the HEAD dim ----------------------
// one wave per token; lane = h*8+g computes score[h][g]; softmax over g.
// At the HBM roofline: 96 MB bf16 read + 64 MB f32 write ~ 25 us ideal.
__global__ __launch_bounds__(256) void attn_k(const unsigned short* __restrict__ QKV,
                                              float* __restrict__ out) {
    __shared__ unsigned short sQ[4][HIDDEN];
    __shared__ unsigned short sK[4][HIDDEN];
    __shared__ unsigned short sV[4][HIDDEN];
    __shared__ float sA[4][64];

    const int t = threadIdx.x, lane = t & 63, wave = t >> 6;
    const int token = blockIdx.x * 4 + wave;
    const size_t base = (size_t)token * HIDDEN;
    const unsigned short* q = QKV + base;
    const unsigned short* k = QKV + (size_t)NTOK * HIDDEN + base;
    const unsigned short* v = QKV + 2 * (size_t)NTOK * HIDDEN + base;

#pragma unroll
    for (int i = 0; i < 2; ++i) {
        const int off = (i * 64 + lane) * 8;
        *(u16x8*)&sQ[wave][off] = *(const u16x8*)&q[off];
        *(u16x8*)&sK[wave][off] = *(const u16x8*)&k[off];
        *(u16x8*)&sV[wave][off] = *(const u16x8*)&v[off];
    }
    __syncthreads();

    const int h = lane >> 3, g = lane & 7;
    float sc = 0.f;
    const unsigned short* Qr = &sQ[wave][h * 128];
    const unsigned short* Kr = &sK[wave][g * 128];
#pragma unroll
    for (int d = 0; d < 128; d += 8) {
        u16x8 qv = *(const u16x8*)&Qr[d];
        u16x8 kv = *(const u16x8*)&Kr[d];
#pragma unroll
        for (int j = 0; j < 8; ++j) sc += b2f(qv[j]) * b2f(kv[j]);
    }
    sc *= -0.08838834764831845f;   // NEGATED scale, faithful to source quirk

    float mx = sc;
#pragma unroll
    for (int o = 1; o < 8; o <<= 1) mx = fmaxf(mx, __shfl_xor(mx, o, 64));
    const float e = __expf(sc - mx);
    float sm = e;
#pragma unroll
    for (int o = 1; o < 8; o <<= 1) sm += __shfl_xor(sm, o, 64);
    sA[wave][lane] = e / sm;
    __syncthreads();

    const int c = lane & 7;        // 16-wide d-chunk within head
    float ov[16];
#pragma unroll
    for (int j = 0; j < 16; ++j) ov[j] = 0.f;
    const float* Ar = &sA[wave][h * 8];
#pragma unroll
    for (int gg = 0; gg < 8; ++gg) {
        const float a = Ar[gg];
        const unsigned short* Vr = &sV[wave][gg * 128 + c * 16];
#pragma unroll
        for (int j = 0; j < 16; ++j) ov[j] += a * b2f(Vr[j]);
    }
    float* op = out + base + lane * 16;   // lane*16 == h*128 + c*16
#pragma unroll
    for (int j = 0; j < 16; j += 4) {
        float4 r = make_float4(ov[j], ov[j + 1], ov[j + 2], ov[j + 3]);
        *(float4*)&op[j] = r;
    }
}

extern "C" void kernel_launch(void* const* d_in, const int* in_sizes, int n_in,
                              void* d_out, int out_size, void* d_ws, size_t ws_size,
                              hipStream_t stream) {
    const float* x1 = (const float*)d_in[0];
    const float* Wq = (const float*)d_in[1];
    const float* bq = (const float*)d_in[2];
    const float* Wk = (const float*)d_in[3];
    const float* bk = (const float*)d_in[4];
    const float* Wv = (const float*)d_in[5];
    const float* bv = (const float*)d_in[6];
    float* out = (float*)d_out;

    // workspace layout (bf16 as ushort): Xb | Wb(q,k,v) | QKV  -> 140.5 MB
    unsigned short* Xb  = (unsigned short*)d_ws;
    unsigned short* Wb  = Xb + (size_t)NTOK * HIDDEN;
    unsigned short* QKV = Wb + 3 * (size_t)HIDDEN * HIDDEN;

    cvt_all<<<2048, 256, 0, stream>>>((const float4*)x1, (const float4*)Wq,
                                      (const float4*)Wk, (const float4*)Wv,
                                      (u16x4*)Xb);

    qkv_gemm<<<dim3(1536), 256, 0, stream>>>(Xb, Wb, bq, bk, bv, QKV);

    attn_k<<<NTOK / 4, 256, 0, stream>>>(QKV, out);
}